// Round 8
// baseline (61.417 us; speedup 1.0000x reference)
//
#include <hip/hip_runtime.h>
#include <hip/hip_bf16.h>

#define N_NODES 120000
#define F       64

typedef __attribute__((ext_vector_type(8))) short bf16x8;   // 4 VGPRs
typedef __attribute__((ext_vector_type(4))) float f32x4;    // MFMA C/D
typedef __attribute__((ext_vector_type(4))) int   int4v;    // clang vector (nt-builtin ok)
typedef __attribute__((ext_vector_type(4))) unsigned int uint4v;
typedef __attribute__((ext_vector_type(4))) float float4v;

static __device__ __forceinline__ unsigned short f2bf(float x) {
    return __hip_bfloat16_raw(__float2bfloat16(x)).x;   // RNE
}
static __device__ __forceinline__ float u2f(unsigned int x) {
    return __uint_as_float(x);
}

// Pack theta_w/phi_w into per-lane MFMA B-operand fragments (bf16).
__global__ void prep_weights(const float* __restrict__ theta_w,
                             const float* __restrict__ phi_w,
                             unsigned short* __restrict__ wfrag)  // [16][64][8]
{
    const int t    = threadIdx.x;          // 0..1023
    const int slot = t >> 6, lane = t & 63;
    const int mat  = slot >> 3, c = (slot >> 1) & 3, kb = slot & 1;
    const float* W = mat ? phi_w : theta_w;
    const int k0   = kb * 32 + ((lane >> 4) * 8);
    const int col  = c * 16 + (lane & 15);
    bf16x8 v;
    #pragma unroll
    for (int e = 0; e < 8; ++e)
        v[e] = (short)f2bf(W[(k0 + e) * F + col]);
    ((bf16x8*)wfrag)[slot * 64 + lane] = v;
}

// Kernel 1 (MFMA): T16 = bf16(feat@theta); B16 = bf16(T + feat@phi + biases)
__global__ __launch_bounds__(256) void edgeconv_mfma(
    const float* __restrict__ feat,
    const unsigned short* __restrict__ wfrag,
    const float* __restrict__ theta_b,
    const float* __restrict__ phi_b,
    unsigned short* __restrict__ T16,
    unsigned short* __restrict__ B16)
{
    const int lane = threadIdx.x & 63;
    const int wv   = threadIdx.x >> 6;
    const int tile = blockIdx.x * 4 + wv;
    const int r0   = tile * 16;

    const bf16x8* wf = (const bf16x8*)wfrag;
    bf16x8 wt[4][2], wp[4][2];
    #pragma unroll
    for (int c = 0; c < 4; ++c) {
        #pragma unroll
        for (int kb = 0; kb < 2; ++kb) {
            wt[c][kb] = wf[((0 * 4 + c) * 2 + kb) * 64 + lane];
            wp[c][kb] = wf[((1 * 4 + c) * 2 + kb) * 64 + lane];
        }
    }

    const int arow = r0 + (lane & 15);
    const int k0   = (lane >> 4) * 8;
    const float4* f0 = (const float4*)(feat + arow * F + k0);
    const float4* f1 = (const float4*)(feat + arow * F + 32 + k0);
    float4 a0 = f0[0], a1 = f0[1];
    float4 a2 = f1[0], a3 = f1[1];
    bf16x8 afr0, afr1;
    afr0[0]=(short)f2bf(a0.x); afr0[1]=(short)f2bf(a0.y); afr0[2]=(short)f2bf(a0.z); afr0[3]=(short)f2bf(a0.w);
    afr0[4]=(short)f2bf(a1.x); afr0[5]=(short)f2bf(a1.y); afr0[6]=(short)f2bf(a1.z); afr0[7]=(short)f2bf(a1.w);
    afr1[0]=(short)f2bf(a2.x); afr1[1]=(short)f2bf(a2.y); afr1[2]=(short)f2bf(a2.z); afr1[3]=(short)f2bf(a2.w);
    afr1[4]=(short)f2bf(a3.x); afr1[5]=(short)f2bf(a3.y); afr1[6]=(short)f2bf(a3.z); afr1[7]=(short)f2bf(a3.w);

    f32x4 accT[4], accP[4];
    #pragma unroll
    for (int c = 0; c < 4; ++c) { accT[c] = (f32x4)(0.f); accP[c] = (f32x4)(0.f); }

    #pragma unroll
    for (int c = 0; c < 4; ++c) {
        accT[c] = __builtin_amdgcn_mfma_f32_16x16x32_bf16(afr0, wt[c][0], accT[c], 0, 0, 0);
        accT[c] = __builtin_amdgcn_mfma_f32_16x16x32_bf16(afr1, wt[c][1], accT[c], 0, 0, 0);
        accP[c] = __builtin_amdgcn_mfma_f32_16x16x32_bf16(afr0, wp[c][0], accP[c], 0, 0, 0);
        accP[c] = __builtin_amdgcn_mfma_f32_16x16x32_bf16(afr1, wp[c][1], accP[c], 0, 0, 0);
    }

    const int colbase = lane & 15;
    const int rowbase = (lane >> 4) * 4;
    #pragma unroll
    for (int c = 0; c < 4; ++c) {
        const int col  = c * 16 + colbase;
        const float bo = theta_b[col] + phi_b[col];
        #pragma unroll
        for (int rg = 0; rg < 4; ++rg) {
            const int r = r0 + rowbase + rg;
            const float t = accT[c][rg];
            T16[r * F + col] = f2bf(t);
            B16[r * F + col] = f2bf(t + accP[c][rg] + bo);
        }
    }
}

// Kernel 2: out[v][o] = B[v][o] - min_k T[nbr[v][k]][o]
// 8 nodes/wave, 8 lanes/node, uint4 gathers (8 random 128B rows / instruction).
// Streaming traffic (nbr, B, out) is NON-TEMPORAL so L2 holds only T rows.
__global__ __launch_bounds__(256) void edgeconv_minmax(
    const int* __restrict__ nbr,              // [N,16] int32
    const unsigned short* __restrict__ T16,   // [N,64] bf16
    const unsigned short* __restrict__ B16,   // [N,64] bf16
    float* __restrict__ out)                  // [N,64] f32
{
    const int tid  = threadIdx.x;
    const int lane = tid & 63;
    const int wv   = tid >> 6;
    const int sub  = lane >> 3;      // node within wave, 0..7
    const int j    = lane & 7;       // lane covers cols 8j..8j+7 (16B)
    const int v    = blockIdx.x * 32 + wv * 8 + sub;

    // 16 neighbor indices, non-temporal (8 lanes/node same addr -> broadcast)
    const int4v* nb4 = (const int4v*)(nbr + v * 16);
    int4v i0 = __builtin_nontemporal_load(nb4 + 0);
    int4v i1 = __builtin_nontemporal_load(nb4 + 1);
    int4v i2 = __builtin_nontemporal_load(nb4 + 2);
    int4v i3 = __builtin_nontemporal_load(nb4 + 3);
    int idx[16] = { i0[0], i0[1], i0[2], i0[3],
                    i1[0], i1[1], i1[2], i1[3],
                    i2[0], i2[1], i2[2], i2[3],
                    i3[0], i3[1], i3[2], i3[3] };

    const char* tb = (const char*)T16 + (j << 4);

    // 16 independent 16B gathers per lane (default caching: keep T in L2).
    uint4v u[16];
    #pragma unroll
    for (int k = 0; k < 16; ++k)
        u[k] = *(const uint4v*)(tb + (((unsigned int)idx[k]) << 7));

    // 8 running mins: even cols via <<16, odd cols via raw-as-f32
    // (raw dword's high half IS a valid f32; low-mantissa garbage <= 2^-8 rel).
    float mn[8];
    mn[0] = u2f(u[0][0] << 16); mn[1] = u2f(u[0][0]);
    mn[2] = u2f(u[0][1] << 16); mn[3] = u2f(u[0][1]);
    mn[4] = u2f(u[0][2] << 16); mn[5] = u2f(u[0][2]);
    mn[6] = u2f(u[0][3] << 16); mn[7] = u2f(u[0][3]);
    #pragma unroll
    for (int k = 1; k < 16; ++k) {
        mn[0] = fminf(mn[0], u2f(u[k][0] << 16)); mn[1] = fminf(mn[1], u2f(u[k][0]));
        mn[2] = fminf(mn[2], u2f(u[k][1] << 16)); mn[3] = fminf(mn[3], u2f(u[k][1]));
        mn[4] = fminf(mn[4], u2f(u[k][2] << 16)); mn[5] = fminf(mn[5], u2f(u[k][2]));
        mn[6] = fminf(mn[6], u2f(u[k][3] << 16)); mn[7] = fminf(mn[7], u2f(u[k][3]));
    }

    const uint4v bu = __builtin_nontemporal_load(
        (const uint4v*)((const char*)B16 + (((unsigned int)v) << 7) + (j << 4)));
    float4v r0, r1;
    r0[0] = u2f(bu[0] << 16)         - mn[0];
    r0[1] = u2f(bu[0] & 0xffff0000u) - mn[1];
    r0[2] = u2f(bu[1] << 16)         - mn[2];
    r0[3] = u2f(bu[1] & 0xffff0000u) - mn[3];
    r1[0] = u2f(bu[2] << 16)         - mn[4];
    r1[1] = u2f(bu[2] & 0xffff0000u) - mn[5];
    r1[2] = u2f(bu[3] << 16)         - mn[6];
    r1[3] = u2f(bu[3] & 0xffff0000u) - mn[7];

    float* op = out + v * F + j * 8;
    __builtin_nontemporal_store(r0, (float4v*)op);
    __builtin_nontemporal_store(r1, (float4v*)(op + 4));
}

extern "C" void kernel_launch(void* const* d_in, const int* in_sizes, int n_in,
                              void* d_out, int out_size, void* d_ws, size_t ws_size,
                              hipStream_t stream) {
    const float* feat    = (const float*)d_in[0];
    const int*   nbr     = (const int*)  d_in[1];
    const float* theta_w = (const float*)d_in[2];
    const float* theta_b = (const float*)d_in[3];
    const float* phi_w   = (const float*)d_in[4];
    const float* phi_b   = (const float*)d_in[5];
    float* out = (float*)d_out;

    unsigned short* wfrag = (unsigned short*)d_ws;                        // 16 KB
    unsigned short* T16   = (unsigned short*)((char*)d_ws + 16384);      // 15.36 MB
    unsigned short* B16   = (unsigned short*)((char*)d_ws + 16384 + 15360000);

    prep_weights<<<1, 1024, 0, stream>>>(theta_w, phi_w, wfrag);
    edgeconv_mfma<<<N_NODES / 64, 256, 0, stream>>>(feat, wfrag, theta_b, phi_b, T16, B16);
    edgeconv_minmax<<<N_NODES / 32, 256, 0, stream>>>(nbr, T16, B16, out);
}